// Round 26
// baseline (24.042 us; speedup 1.0000x reference)
//
#include <hip/hip_runtime.h>

// SphericalVectorPool on MI355X — fragment-direct E generation (no E round-trip).
// R25 post-mortem: DS-issue-bound (28 DS instr/iter ~212 cyc x 32 waves/CU x 8
// iters = 22.6us = measured wall). This round: each lane owns k=col and
// computes its MFMA A-fragment E = exp2(nmu[col]*d_src) DIRECTLY (32 exps/iter,
// marginal trans cost ~1.6cyc/instr per R24). Only d (f32) and w (f16) pass
// through LDS — broadcast-heavy reads (4-16 unique addrs/instr, same-address
// broadcast free). DS: 21 instrs/iter, mostly cheap. No cvt-chain, no odd
// corrections, no eT. A/B share src-ascending K order (permutation cancels,
// R22-validated); D-map (m89): lane holds D[rows k=4*grp+r][col=comp].

constexpr int NR    = 16;
constexpr int BATCH = 2;
constexpr int NSRC  = 2048;
constexpr int MOUT  = 2048;

typedef __fp16 h2 __attribute__((ext_vector_type(2)));
typedef _Float16 f16x8 __attribute__((ext_vector_type(8)));
typedef float f32x4 __attribute__((ext_vector_type(4)));

__global__ __launch_bounds__(128, 1) void svp_kernel(
    const float* __restrict__ f,       // [B,N]
    const float* __restrict__ coords,  // [B,N,3]
    const float* __restrict__ outc,    // [B,M,3]
    const float* __restrict__ mu,      // [16]
    const float* __restrict__ rn,      // [16]
    const float* __restrict__ an0,     // [1]
    const float* __restrict__ an1,     // [1]
    float* __restrict__ out)           // [B,M,64]
{
    const int tid  = threadIdx.x;
    const int lane = tid & 63;
    const int w    = tid >> 6;                // wave in block: 0..1
    const int anchor = blockIdx.x;            // 0..4095
    const int b = anchor >> 11;
    const int col = lane & 15;
    const int grp = lane >> 4;

    __shared__ __align__(16) float dS[2][128];             // per-wave d values
    __shared__ __align__(16) unsigned short wS[2][4][132]; // per-wave w comps
    __shared__ __align__(16) f32x4 red[64];                // wave1 acc park

    const float NL2E = -1.44269504088896340736f;

    // each lane owns k = col: one exp2 coefficient in a VGPR
    const float nmu_l = mu[col] * NL2E;

    const float Rx = outc[(size_t)anchor * 3 + 0];
    const float Ry = outc[(size_t)anchor * 3 + 1];
    const float Rz = outc[(size_t)anchor * 3 + 2];

    f32x4 acc = {0.f, 0.f, 0.f, 0.f};

    const float* cb = coords + (size_t)b * NSRC * 3;
    const float* fb = f + (size_t)b * NSRC;

    for (int i = 0; i < 8; ++i) {             // 8 iterations, 128 src each
        const int s0 = w * (NSRC / 2) + i * 128 + 2 * lane;  // lane: s0, s0+1
        const float2 c0 = *(const float2*)(cb + (size_t)s0 * 3);      // x0 y0
        const float2 c1 = *(const float2*)(cb + (size_t)s0 * 3 + 2);  // z0 x1
        const float2 c2 = *(const float2*)(cb + (size_t)s0 * 3 + 4);  // y1 z1
        const float2 f2 = *(const float2*)(fb + s0);

        const float dx0 = c0.x - Rx, dy0 = c0.y - Ry, dz0 = c1.x - Rz;
        const float dx1 = c1.y - Rx, dy1 = c2.x - Ry, dz1 = c2.y - Rz;

        const float sq0 = dx0 * dx0 + dy0 * dy0 + dz0 * dz0;
        const float sq1 = dx1 * dx1 + dy1 * dy1 + dz1 * dz1;
        const float ri0 = __builtin_amdgcn_rsqf(sq0);
        const float ri1 = __builtin_amdgcn_rsqf(sq1);
        const float d0 = sq0 * ri0, d1 = sq1 * ri1;
        const float t0 = f2.x * ri0, t1 = f2.y * ri1;

        // share d (f32, exact) and w (f16) with the wave via LDS
        *(float2*)&dS[w][2 * lane] = make_float2(d0, d1);      // ds_write_b64
        *(unsigned*)&wS[w][0][2 * lane] =
            __builtin_bit_cast(unsigned, __builtin_amdgcn_cvt_pkrtz(f2.x, f2.y));
        *(unsigned*)&wS[w][1][2 * lane] =
            __builtin_bit_cast(unsigned, __builtin_amdgcn_cvt_pkrtz(t0 * dx0, t1 * dx1));
        *(unsigned*)&wS[w][2][2 * lane] =
            __builtin_bit_cast(unsigned, __builtin_amdgcn_cvt_pkrtz(t0 * dy0, t1 * dy1));
        *(unsigned*)&wS[w][3][2 * lane] =
            __builtin_bit_cast(unsigned, __builtin_amdgcn_cvt_pkrtz(t0 * dz0, t1 * dz1));
        // same-wave cross-lane via LDS: DS ops are wave-ordered (R22/R25-validated)

        // 4 MFMA chunks of 32 sources, fragment-direct A
#pragma unroll
        for (int c = 0; c < 4; ++c) {
            // d for this lane's K-slice: srcs {32c+4g..+3} and {+16}
            const float4 dlo = *(const float4*)&dS[w][32 * c + 4 * grp];
            const float4 dhi = *(const float4*)&dS[w][32 * c + 16 + 4 * grp];
            const float e0 = __builtin_amdgcn_exp2f(dlo.x * nmu_l);
            const float e1 = __builtin_amdgcn_exp2f(dlo.y * nmu_l);
            const float e2 = __builtin_amdgcn_exp2f(dlo.z * nmu_l);
            const float e3 = __builtin_amdgcn_exp2f(dlo.w * nmu_l);
            const float e4 = __builtin_amdgcn_exp2f(dhi.x * nmu_l);
            const float e5 = __builtin_amdgcn_exp2f(dhi.y * nmu_l);
            const float e6 = __builtin_amdgcn_exp2f(dhi.z * nmu_l);
            const float e7 = __builtin_amdgcn_exp2f(dhi.w * nmu_l);
            union { h2 h[4]; f16x8 v; } av;
            av.h[0] = __builtin_amdgcn_cvt_pkrtz(e0, e1);
            av.h[1] = __builtin_amdgcn_cvt_pkrtz(e2, e3);
            av.h[2] = __builtin_amdgcn_cvt_pkrtz(e4, e5);
            av.h[3] = __builtin_amdgcn_cvt_pkrtz(e6, e7);

            // w for comp=col&3 at the same K-slice (src-ascending order)
            union { uint2 u[2]; f16x8 v; } bv;
            bv.u[0] = *(const uint2*)&wS[w][col & 3][32 * c + 4 * grp];
            bv.u[1] = *(const uint2*)&wS[w][col & 3][32 * c + 16 + 4 * grp];

            acc = __builtin_amdgcn_mfma_f32_16x16x32_f16(av.v, bv.v, acc, 0, 0, 0);
        }
    }

    // cross-wave combine
    if (w == 1) red[lane] = acc;
    __syncthreads();
    if (w == 0) {
        acc += red[lane];
        // D[row=4*grp+r][col]: col = component, row = k (m89-verified map)
        if (col < 4) {
            const float4 r4 = *(const float4*)&rn[4 * grp];
            const float an = (col == 0) ? an0[0] : an1[0];
            float4 o;
            o.x = acc[0] * r4.x * an;
            o.y = acc[1] * r4.y * an;
            o.z = acc[2] * r4.z * an;
            o.w = acc[3] * r4.w * an;
            *(float4*)&out[(size_t)anchor * 64 + col * 16 + 4 * grp] = o;
        }
    }
}

extern "C" void kernel_launch(void* const* d_in, const int* in_sizes, int n_in,
                              void* d_out, int out_size, void* d_ws, size_t ws_size,
                              hipStream_t stream) {
    const float* f      = (const float*)d_in[0];
    const float* coords = (const float*)d_in[1];
    const float* outc   = (const float*)d_in[2];
    const float* mu     = (const float*)d_in[3];
    const float* rn     = (const float*)d_in[4];
    const float* an0    = (const float*)d_in[5];
    const float* an1    = (const float*)d_in[6];
    float* out = (float*)d_out;

    const int anchors = BATCH * MOUT;              // 4096 blocks, 2 waves each
    svp_kernel<<<anchors, 128, 0, stream>>>(f, coords, outc, mu, rn, an0, an1, out);
}